// Round 1
// baseline (104.411 us; speedup 1.0000x reference)
//
#include <hip/hip_runtime.h>

#define BB 8
#define XX 256
#define CC 256
#define TC 4   // c-rows per block

// Thread = d (0..255). Block handles (b, c0..c0+TC-1).
// Exact fp32 op-order match with the numpy reference:
//  - sequential sum over x (numpy axis-1 reduce is sequential accumulation)
//  - no FMA contraction in the sensitive chain (__f*_rn intrinsics)
//  - IEEE divides; softmax emulated literally (max-subtract, exp, normalize, compare)
__global__ __launch_bounds__(256) void mahal_mask_kernel(
    const float* __restrict__ amp,   // (B,X,C)
    const float* __restrict__ ph,    // (B,X,C)
    const float* __restrict__ A,     // (C,C) - only diag used
    const float* __restrict__ wAp,   // scalar
    const float* __restrict__ wPp,   // scalar
    const float* __restrict__ gu,    // (B,C,C,2)
    float* __restrict__ out)         // (C,C), pre-zeroed
{
    const int d  = threadIdx.x;
    const int c0 = blockIdx.x * TC;
    const int b  = blockIdx.y;

    const float wa = wAp[0];
    const float wp = wPp[0];

    // Stage the TC "c" columns of amp and ph: cols[x][0..TC-1]=amp, [TC..2TC-1]=ph
    __shared__ float cols[XX][2 * TC];           // 8 KB
    for (int idx = threadIdx.x; idx < XX * TC; idx += 256) {
        int x = idx >> 2;            // TC == 4
        int j = idx & 3;
        cols[x][j]      = amp[(size_t)b * XX * CC + (size_t)x * CC + (c0 + j)];
        cols[x][TC + j] = ph [(size_t)b * XX * CC + (size_t)x * CC + (c0 + j)];
    }
    __syncthreads();

    const float dAd = A[(size_t)d * CC + d];

    float acc[TC];
#pragma unroll
    for (int j = 0; j < TC; ++j) acc[j] = 0.0f;

    const float* ampbd = amp + (size_t)b * XX * CC + d;
    const float* phbd  = ph  + (size_t)b * XX * CC + d;

#pragma unroll 4
    for (int x = 0; x < XX; ++x) {
        float av = ampbd[(size_t)x * CC];   // coalesced across d
        float pv = phbd [(size_t)x * CC];
#pragma unroll
        for (int j = 0; j < TC; ++j) {
            float adf   = __fsub_rn(cols[x][j], av);        // amp_c - amp_d
            float pdf   = __fsub_rn(cols[x][TC + j], pv);   // ph_c  - ph_d
            float fused = __fadd_rn(__fmul_rn(wa, adf), __fmul_rn(wp, pdf));
            float temp  = __fmul_rn(dAd, fused);
            acc[j]      = __fadd_rn(acc[j], __fmul_rn(temp, temp));  // sequential in x
        }
    }

    // exp_dist with diagonal zeroed
    float ed[TC];
#pragma unroll
    for (int j = 0; j < TC; ++j) {
        float dist = __fadd_rn(acc[j], 1e-10f);
        float e    = __fdiv_rn(1.0f, dist);
        ed[j]      = (d == c0 + j) ? 0.0f : e;
    }

    // Row max over all 256 d's, per c-row: wave reduce + cross-wave via LDS
    __shared__ float wmax[TC][4];
    const int wave = threadIdx.x >> 6;
    const int lane = threadIdx.x & 63;
#pragma unroll
    for (int j = 0; j < TC; ++j) {
        float v = ed[j];
#pragma unroll
        for (int m = 1; m < 64; m <<= 1) v = fmaxf(v, __shfl_xor(v, m));
        if (lane == 0) wmax[j][wave] = v;
    }
    __syncthreads();

#pragma unroll
    for (int j = 0; j < TC; ++j) {
        const int c = c0 + j;
        float em = fmaxf(fmaxf(wmax[j][0], wmax[j][1]), fmaxf(wmax[j][2], wmax[j][3]));
        float p;
        if (d == c) {
            p = 0.99f;                                   // (0*off + 1)*0.99
        } else {
            p = __fmul_rn(__fdiv_rn(ed[j], em), 0.99f);  // (e/em * 1 + 0)*0.99
        }
        float logit = logf(__fdiv_rn(p, __fsub_rn(1.0f, p)));

        const float* g = gu + (((size_t)b * CC + c) * CC + d) * 2;
        float u0 = g[0];
        float u1 = g[1];
        float g0 = -logf(-logf(u0));
        float g1 = -logf(-logf(u1));

        // softmax([logit+g0, -logit+g1]) literally, then compare y0 > y1
        float a0 = __fadd_rn(logit, g0);
        float a1 = __fadd_rn(-logit, g1);
        float m  = fmaxf(a0, a1);
        float e0 = expf(__fsub_rn(a0, m));
        float e1 = expf(__fsub_rn(a1, m));
        float s  = __fadd_rn(e0, e1);
        float y0 = __fdiv_rn(e0, s);
        float y1 = __fdiv_rn(e1, s);
        if (y0 > y1) {
            atomicAdd(&out[(size_t)c * CC + d], 0.125f);  // mean over B=8: exact dyadic sum
        }
    }
}

extern "C" void kernel_launch(void* const* d_in, const int* in_sizes, int n_in,
                              void* d_out, int out_size, void* d_ws, size_t ws_size,
                              hipStream_t stream) {
    const float* amp = (const float*)d_in[0];
    const float* ph  = (const float*)d_in[1];
    const float* A   = (const float*)d_in[2];
    const float* wa  = (const float*)d_in[3];
    const float* wp  = (const float*)d_in[4];
    const float* gu  = (const float*)d_in[5];
    float* out = (float*)d_out;

    // d_out is poisoned 0xAA before every launch; we accumulate via atomics.
    hipMemsetAsync(out, 0, (size_t)CC * CC * sizeof(float), stream);

    dim3 grid(CC / TC, BB);
    mahal_mask_kernel<<<grid, 256, 0, stream>>>(amp, ph, A, wa, wp, gu, out);
}